// Round 1
// baseline (3007.467 us; speedup 1.0000x reference)
//
#include <hip/hip_runtime.h>
#include <math.h>

namespace {

constexpr int B  = 4;
constexpr int N  = 2048;
constexpr int C  = 768;
constexpr int H  = 12;
constexpr int Dh = 64;
constexpr int M  = B * N;      // 8192
constexpr int C3 = 3 * C;      // 2304
constexpr float SCALE_F = 0.125f;

// out[m][n] = bias[n] + sum_k A[m][k] * Bw[n][k]
// A: [Mdim][K] row-major, Bw: [Ndim][K] row-major (torch Linear weight layout)
template <int BM, int BN, int BK>
__global__ __launch_bounds__(256) void gemm_bt_bias(
    const float* __restrict__ A, const float* __restrict__ Bw,
    const float* __restrict__ bias, float* __restrict__ out,
    int Mdim, int Ndim, int K) {
  __shared__ float As[BK][BM + 1];
  __shared__ float Bs[BK][BN + 1];
  const int bm = blockIdx.x * BM;
  const int bn = blockIdx.y * BN;
  const int t  = threadIdx.x;           // 256 threads
  const int tx = t & 15, ty = t >> 4;

  float acc[4][4] = {};

  for (int k0 = 0; k0 < K; k0 += BK) {
#pragma unroll
    for (int i = 0; i < (BM * BK) / 256; ++i) {
      int idx = i * 256 + t;
      int kk  = idx & (BK - 1);
      int mm  = idx / BK;
      As[kk][mm] = A[(size_t)(bm + mm) * K + k0 + kk];
    }
#pragma unroll
    for (int i = 0; i < (BN * BK) / 256; ++i) {
      int idx = i * 256 + t;
      int kk  = idx & (BK - 1);
      int nn  = idx / BK;
      Bs[kk][nn] = Bw[(size_t)(bn + nn) * K + k0 + kk];
    }
    __syncthreads();
#pragma unroll
    for (int kk = 0; kk < BK; ++kk) {
      float a[4], b[4];
#pragma unroll
      for (int i = 0; i < 4; ++i) a[i] = As[kk][ty * 4 + i];
#pragma unroll
      for (int j = 0; j < 4; ++j) b[j] = Bs[kk][tx * 4 + j];
#pragma unroll
      for (int i = 0; i < 4; ++i)
#pragma unroll
        for (int j = 0; j < 4; ++j) acc[i][j] += a[i] * b[j];
    }
    __syncthreads();
  }

#pragma unroll
  for (int i = 0; i < 4; ++i) {
    int m = bm + ty * 4 + i;
#pragma unroll
    for (int j = 0; j < 4; ++j) {
      int n = bn + tx * 4 + j;
      out[(size_t)m * Ndim + n] = acc[i][j] + bias[n];
    }
  }
}

// Flash-style attention. qkv: [B*N][3C] with c = s*768 + h*64 + d.
// grid: (B*H, N/64), block 256. Thread t: row r = t>>2 of the Q tile,
// d/j sub-range (t&3)*16. Q row lives in registers (pre-scaled).
__global__ __launch_bounds__(256) void attn_fused(
    const float* __restrict__ qkv, float* __restrict__ ctx) {
  const int bh = blockIdx.x;
  const int b  = bh / H, h = bh % H;
  const int qt = blockIdx.y;            // 0..N/64-1
  const int t  = threadIdx.x;
  const int r  = t >> 2;                // 0..63
  const int dq = (t & 3) * 16;          // both the j-slice and the d-slice

  __shared__ float Ks[64][Dh + 4];      // +4 pad: bank spread + 16B align
  __shared__ float Vs[64][Dh + 4];
  __shared__ float Ps[64][64 + 4];

  const size_t base  = (size_t)b * N * C3;
  const float* qbase = qkv + base + 0 * C + h * Dh;
  const float* kbase = qkv + base + 1 * C + h * Dh;
  const float* vbase = qkv + base + 2 * C + h * Dh;

  // Q row -> registers, pre-scaled by 1/sqrt(Dh)
  float qreg[Dh];
  {
    const float* qrow = qbase + (size_t)(qt * 64 + r) * C3;
#pragma unroll
    for (int d = 0; d < Dh; d += 4) {
      float4 v = *reinterpret_cast<const float4*>(qrow + d);
      qreg[d]     = v.x * SCALE_F;
      qreg[d + 1] = v.y * SCALE_F;
      qreg[d + 2] = v.z * SCALE_F;
      qreg[d + 3] = v.w * SCALE_F;
    }
  }

  float mrow = -INFINITY, lrow = 0.f;
  float o[16];
#pragma unroll
  for (int i = 0; i < 16; ++i) o[i] = 0.f;

  for (int kt = 0; kt < N / 64; ++kt) {
    // stage K,V tiles (coalesced: lane reads consecutive d)
#pragma unroll
    for (int i = 0; i < 16; ++i) {
      int idx = i * 256 + t;
      int row = idx >> 6, d = idx & 63;
      Ks[row][d] = kbase[(size_t)(kt * 64 + row) * C3 + d];
      Vs[row][d] = vbase[(size_t)(kt * 64 + row) * C3 + d];
    }
    __syncthreads();

    // S[r][j] for this thread's 16 columns
    float s[16];
#pragma unroll
    for (int jj = 0; jj < 16; ++jj) {
      int j = dq + jj;
      float acc = 0.f;
#pragma unroll
      for (int d = 0; d < Dh; d += 4) {
        float4 kv = *reinterpret_cast<const float4*>(&Ks[j][d]);
        acc += qreg[d] * kv.x + qreg[d + 1] * kv.y +
               qreg[d + 2] * kv.z + qreg[d + 3] * kv.w;
      }
      s[jj] = acc;
    }

    // online softmax: row reduce across 4-lane group (aligned within wave)
    float mx = s[0];
#pragma unroll
    for (int jj = 1; jj < 16; ++jj) mx = fmaxf(mx, s[jj]);
    mx = fmaxf(mx, __shfl_xor(mx, 1));
    mx = fmaxf(mx, __shfl_xor(mx, 2));
    float newm = fmaxf(mrow, mx);
    float corr = __expf(mrow - newm);   // first tile: exp(-inf)=0
    float psum = 0.f;
#pragma unroll
    for (int jj = 0; jj < 16; ++jj) {
      float p = __expf(s[jj] - newm);
      Ps[r][dq + jj] = p;
      psum += p;
    }
    psum += __shfl_xor(psum, 1);
    psum += __shfl_xor(psum, 2);
    lrow = lrow * corr + psum;
    mrow = newm;
#pragma unroll
    for (int i = 0; i < 16; ++i) o[i] *= corr;

    // Ps row r is written and read only by the same 4-lane group (same wave),
    // so no extra barrier needed before PV; Vs was synced above.
    for (int j = 0; j < 64; ++j) {
      float p = Ps[r][j];
#pragma unroll
      for (int dd = 0; dd < 16; dd += 4) {
        float4 vv = *reinterpret_cast<const float4*>(&Vs[j][dq + dd]);
        o[dd]     += p * vv.x;
        o[dd + 1] += p * vv.y;
        o[dd + 2] += p * vv.z;
        o[dd + 3] += p * vv.w;
      }
    }
    __syncthreads();  // before next iteration overwrites Ks/Vs
  }

  const float inv = 1.f / lrow;
  float* orow = ctx + (size_t)(b * N + qt * 64 + r) * C + h * Dh + dq;
#pragma unroll
  for (int dd = 0; dd < 16; ++dd) orow[dd] = o[dd] * inv;
}

}  // namespace

extern "C" void kernel_launch(void* const* d_in, const int* in_sizes, int n_in,
                              void* d_out, int out_size, void* d_ws, size_t ws_size,
                              hipStream_t stream) {
  const float* x      = (const float*)d_in[0];
  const float* qkv_w  = (const float*)d_in[1];
  const float* qkv_b  = (const float*)d_in[2];
  const float* proj_w = (const float*)d_in[3];
  const float* proj_b = (const float*)d_in[4];
  float* out = (float*)d_out;

  float* qkv = (float*)d_ws;                 // [M][C3]  75.5 MB
  float* ctx = qkv + (size_t)M * C3;         // [M][C]   25.2 MB

  dim3 blk(256);
  gemm_bt_bias<64, 64, 16>
      <<<dim3(M / 64, C3 / 64), blk, 0, stream>>>(x, qkv_w, qkv_b, qkv, M, C3, C);
  attn_fused<<<dim3(B * H, N / 64), blk, 0, stream>>>(qkv, ctx);
  gemm_bt_bias<64, 64, 16>
      <<<dim3(M / 64, C / 64), blk, 0, stream>>>(ctx, proj_w, proj_b, out, M, C, C);
}

// Round 2
// 875.113 us; speedup vs baseline: 3.4367x; 3.4367x over previous
//
#include <hip/hip_runtime.h>
#include <math.h>

typedef __attribute__((ext_vector_type(8))) short short8;
typedef __attribute__((ext_vector_type(4))) float f32x4;

namespace {

constexpr int B  = 4;
constexpr int N  = 2048;
constexpr int C  = 768;
constexpr int H  = 12;
constexpr int Dh = 64;
constexpr int M  = B * N;      // 8192
constexpr int C3 = 3 * C;      // 2304

__device__ inline unsigned short f2bf(float x) {        // RTNE f32 -> bf16
  unsigned int u = __float_as_uint(x);
  return (unsigned short)((u + 0x7fffu + ((u >> 16) & 1u)) >> 16);
}

// ---------------- fp32 SIMT GEMM (proj): out = A @ Bw^T + bias ----------------
template <int BM, int BN, int BK>
__global__ __launch_bounds__(256) void gemm_bt_bias(
    const float* __restrict__ A, const float* __restrict__ Bw,
    const float* __restrict__ bias, float* __restrict__ out,
    int Mdim, int Ndim, int K) {
  __shared__ float As[BK][BM + 1];
  __shared__ float Bs[BK][BN + 1];
  const int bm = blockIdx.x * BM;
  const int bn = blockIdx.y * BN;
  const int t  = threadIdx.x;
  const int tx = t & 15, ty = t >> 4;

  float acc[4][4] = {};

  for (int k0 = 0; k0 < K; k0 += BK) {
#pragma unroll
    for (int i = 0; i < (BM * BK) / 256; ++i) {
      int idx = i * 256 + t;
      int kk  = idx & (BK - 1);
      int mm  = idx / BK;
      As[kk][mm] = A[(size_t)(bm + mm) * K + k0 + kk];
    }
#pragma unroll
    for (int i = 0; i < (BN * BK) / 256; ++i) {
      int idx = i * 256 + t;
      int kk  = idx & (BK - 1);
      int nn  = idx / BK;
      Bs[kk][nn] = Bw[(size_t)(bn + nn) * K + k0 + kk];
    }
    __syncthreads();
#pragma unroll
    for (int kk = 0; kk < BK; ++kk) {
      float a[4], b[4];
#pragma unroll
      for (int i = 0; i < 4; ++i) a[i] = As[kk][ty * 4 + i];
#pragma unroll
      for (int j = 0; j < 4; ++j) b[j] = Bs[kk][tx * 4 + j];
#pragma unroll
      for (int i = 0; i < 4; ++i)
#pragma unroll
        for (int j = 0; j < 4; ++j) acc[i][j] += a[i] * b[j];
    }
    __syncthreads();
  }

#pragma unroll
  for (int i = 0; i < 4; ++i) {
    int m = bm + ty * 4 + i;
#pragma unroll
    for (int j = 0; j < 4; ++j) {
      int n = bn + tx * 4 + j;
      out[(size_t)m * Ndim + n] = acc[i][j] + bias[n];
    }
  }
}

// ------------- QKV GEMM: fp32 compute, bf16 output, SCALE folded into Q -------------
__global__ __launch_bounds__(256) void gemm_qkv_bf16(
    const float* __restrict__ A, const float* __restrict__ Bw,
    const float* __restrict__ bias, unsigned short* __restrict__ qkvbf) {
  constexpr int BM = 64, BN = 64, BK = 16, K = C;
  __shared__ float As[BK][BM + 1];
  __shared__ float Bs[BK][BN + 1];
  const int bm = blockIdx.x * BM;
  const int bn = blockIdx.y * BN;
  const int t  = threadIdx.x;
  const int tx = t & 15, ty = t >> 4;

  float acc[4][4] = {};

  for (int k0 = 0; k0 < K; k0 += BK) {
#pragma unroll
    for (int i = 0; i < (BM * BK) / 256; ++i) {
      int idx = i * 256 + t;
      int kk  = idx & (BK - 1);
      int mm  = idx / BK;
      As[kk][mm] = A[(size_t)(bm + mm) * K + k0 + kk];
    }
#pragma unroll
    for (int i = 0; i < (BN * BK) / 256; ++i) {
      int idx = i * 256 + t;
      int kk  = idx & (BK - 1);
      int nn  = idx / BK;
      Bs[kk][nn] = Bw[(size_t)(bn + nn) * K + k0 + kk];
    }
    __syncthreads();
#pragma unroll
    for (int kk = 0; kk < BK; ++kk) {
      float a[4], b[4];
#pragma unroll
      for (int i = 0; i < 4; ++i) a[i] = As[kk][ty * 4 + i];
#pragma unroll
      for (int j = 0; j < 4; ++j) b[j] = Bs[kk][tx * 4 + j];
#pragma unroll
      for (int i = 0; i < 4; ++i)
#pragma unroll
        for (int j = 0; j < 4; ++j) acc[i][j] += a[i] * b[j];
    }
    __syncthreads();
  }

#pragma unroll
  for (int i = 0; i < 4; ++i) {
    size_t m = bm + ty * 4 + i;
    ushort4 pk;
    unsigned short* pks = reinterpret_cast<unsigned short*>(&pk);
#pragma unroll
    for (int j = 0; j < 4; ++j) {
      int n = bn + tx * 4 + j;
      float v = acc[i][j] + bias[n];
      if (n < C) v *= 0.125f;          // fold attention scale into Q (exact)
      pks[j] = f2bf(v);
    }
    *reinterpret_cast<ushort4*>(&qkvbf[m * C3 + bn + tx * 4]) = pk;
  }
}

// ------------- V^T prepass: qkvbf V columns -> vt[b][h][d][n] (bf16) -------------
__global__ __launch_bounds__(256) void vt_prepass(
    const unsigned short* __restrict__ qkvbf, unsigned short* __restrict__ vt) {
  const int bh = blockIdx.x, b = bh / H, h = bh % H;
  const int nt = blockIdx.y;
  __shared__ unsigned short tile[64][72];   // 144B row stride: int4-aligned
  const int t = threadIdx.x;
  const int r = t >> 2, ch = (t & 3) * 16;

  const unsigned short* src =
      qkvbf + (size_t)(b * N + nt * 64 + r) * C3 + 2 * C + h * Dh + ch;
  *reinterpret_cast<int4*>(&tile[r][ch])     = *reinterpret_cast<const int4*>(src);
  *reinterpret_cast<int4*>(&tile[r][ch + 8]) = *reinterpret_cast<const int4*>(src + 8);
  __syncthreads();

  alignas(16) unsigned short vals[16];
#pragma unroll
  for (int i = 0; i < 16; ++i) vals[i] = tile[ch + i][r];   // d = r, n = ch+i
  unsigned short* dst = vt + ((size_t)bh * Dh + r) * N + nt * 64 + ch;
  *reinterpret_cast<int4*>(dst)     = *reinterpret_cast<int4*>(&vals[0]);
  *reinterpret_cast<int4*>(dst + 8) = *reinterpret_cast<int4*>(&vals[8]);
}

// ------------- MFMA flash attention -------------
// grid (B*H, N/64), 256 threads = 4 waves x 16 q-rows. KVBLK=64.
// S^T = mfma(K, Q): lane holds P[q=lane&15][kv=16t+4g+r] (g=lane>>4).
// PV: O^T = mfma(V^T, P^T); P^T B-frags built in-register via __shfl.
__global__ __launch_bounds__(256) void attn_mfma(
    const unsigned short* __restrict__ qkvbf,
    const unsigned short* __restrict__ vt,
    float* __restrict__ ctx) {
  const int bh = blockIdx.x, b = bh / H, h = bh % H;
  const int qt = blockIdx.y;
  const int t = threadIdx.x;
  const int wave = t >> 6, lane = t & 63;
  const int q16 = lane & 15, g = lane >> 4;

  __shared__ alignas(16) char ldsK[64 * 128];   // [64 kv][64 d] bf16, XOR-swizzled
  __shared__ alignas(16) char ldsV[64 * 128];   // [64 d][64 kv] bf16, XOR-swizzled

  const int qglob = qt * 64 + wave * 16 + q16;

  // Q B-frags (k-chunks c=0,1): lane needs Q[q=lane&15][d = c*32 + g*8 + j]
  short8 qf[2];
  {
    const unsigned short* qp = qkvbf + (size_t)(b * N + qglob) * C3 + h * Dh + g * 8;
    int4 v0 = *reinterpret_cast<const int4*>(qp);
    int4 v1 = *reinterpret_cast<const int4*>(qp + 32);
    qf[0] = *reinterpret_cast<short8*>(&v0);
    qf[1] = *reinterpret_cast<short8*>(&v1);
  }

  f32x4 ot[4];
#pragma unroll
  for (int mt = 0; mt < 4; ++mt) ot[mt] = (f32x4){0.f, 0.f, 0.f, 0.f};
  float mrun = -INFINITY, lrun = 0.f;

  // staging indices: thread covers row sr, 32B chunk scB
  const int sr = t >> 2;
  const int scB = (t & 3) * 32;
  const size_t kgbase = (size_t)(b * N) * C3 + C + h * Dh;
  const unsigned short* vtrow = vt + ((size_t)bh * Dh + sr) * N;

  for (int kt = 0; kt < N / 64; ++kt) {
    {  // stage K tile [64 kv][64 d] and V^T tile [64 d][64 kv], both swizzled
      const unsigned short* kp = qkvbf + kgbase + (size_t)(kt * 64 + sr) * C3 + (t & 3) * 16;
      int4 ka = *reinterpret_cast<const int4*>(kp);
      int4 kb = *reinterpret_cast<const int4*>(kp + 8);
      const unsigned short* vp = vtrow + kt * 64 + (t & 3) * 16;
      int4 va = *reinterpret_cast<const int4*>(vp);
      int4 vb = *reinterpret_cast<const int4*>(vp + 8);
      const int base = sr * 128 + scB, sw = (sr & 7) << 4;
      *reinterpret_cast<int4*>(ldsK + ((base) ^ sw))      = ka;
      *reinterpret_cast<int4*>(ldsK + ((base + 16) ^ sw)) = kb;
      *reinterpret_cast<int4*>(ldsV + ((base) ^ sw))      = va;
      *reinterpret_cast<int4*>(ldsV + ((base + 16) ^ sw)) = vb;
    }
    __syncthreads();

    // S^T tiles (4 x 16kv): acc over d chunks
    f32x4 st[4];
#pragma unroll
    for (int mt = 0; mt < 4; ++mt) {
      const int row = 16 * mt + q16, sw = (row & 7) << 4;
      short8 k0 = *reinterpret_cast<const short8*>(ldsK + ((row * 128 + 16 * g) ^ sw));
      short8 k1 = *reinterpret_cast<const short8*>(ldsK + ((row * 128 + 64 + 16 * g) ^ sw));
      f32x4 z = (f32x4){0.f, 0.f, 0.f, 0.f};
      f32x4 p = __builtin_amdgcn_mfma_f32_16x16x32_bf16(k0, qf[0], z, 0, 0, 0);
      st[mt]  = __builtin_amdgcn_mfma_f32_16x16x32_bf16(k1, qf[1], p, 0, 0, 0);
    }

    // online softmax: all 16 kv-values for q=lane&15 live in this lane (+3 peers)
    float mx = st[0][0];
#pragma unroll
    for (int tt = 0; tt < 4; ++tt)
#pragma unroll
      for (int r = 0; r < 4; ++r) mx = fmaxf(mx, st[tt][r]);
    mx = fmaxf(mx, __shfl_xor(mx, 16));
    mx = fmaxf(mx, __shfl_xor(mx, 32));
    const float nm = fmaxf(mrun, mx);
    const float corr = __expf(mrun - nm);
    mrun = nm;

    float ls = 0.f;
    unsigned int w0[4], w1[4];
#pragma unroll
    for (int tt = 0; tt < 4; ++tt) {
      float p0 = __expf(st[tt][0] - nm), p1 = __expf(st[tt][1] - nm);
      float p2 = __expf(st[tt][2] - nm), p3 = __expf(st[tt][3] - nm);
      ls += (p0 + p1) + (p2 + p3);
      w0[tt] = (unsigned)f2bf(p0) | ((unsigned)f2bf(p1) << 16);
      w1[tt] = (unsigned)f2bf(p2) | ((unsigned)f2bf(p3) << 16);
    }
    ls += __shfl_xor(ls, 16);
    ls += __shfl_xor(ls, 32);
    lrun = lrun * corr + ls;
#pragma unroll
    for (int mt = 0; mt < 4; ++mt) ot[mt] = ot[mt] * corr;

    // build PV B-frags: lane needs P[q=lane&15][kv = 32c + 8g + j]
    //   kv -> tile tsel=2c+(g>>1), src group 2(g&1)+(j>=4), reg j&3
    short8 pb[2];
    const int srcA = q16 + ((lane & 16) ? 32 : 0);
    const int srcB = srcA + 16;
    const bool hi = (lane & 32) != 0;
#pragma unroll
    for (int c = 0; c < 2; ++c) {
      unsigned a0l = (unsigned)__shfl((int)w0[2 * c], srcA);
      unsigned a1l = (unsigned)__shfl((int)w1[2 * c], srcA);
      unsigned b0l = (unsigned)__shfl((int)w0[2 * c], srcB);
      unsigned b1l = (unsigned)__shfl((int)w1[2 * c], srcB);
      unsigned a0h = (unsigned)__shfl((int)w0[2 * c + 1], srcA);
      unsigned a1h = (unsigned)__shfl((int)w1[2 * c + 1], srcA);
      unsigned b0h = (unsigned)__shfl((int)w0[2 * c + 1], srcB);
      unsigned b1h = (unsigned)__shfl((int)w1[2 * c + 1], srcB);
      int4 pw;
      pw.x = (int)(hi ? a0h : a0l);
      pw.y = (int)(hi ? a1h : a1l);
      pw.z = (int)(hi ? b0h : b0l);
      pw.w = (int)(hi ? b1h : b1l);
      pb[c] = *reinterpret_cast<short8*>(&pw);
    }

    // PV: O^T[d][q] += V^T[d][kv] * P^T[kv][q]
#pragma unroll
    for (int mt = 0; mt < 4; ++mt) {
      const int row = 16 * mt + q16, sw = (row & 7) << 4;
      short8 v0 = *reinterpret_cast<const short8*>(ldsV + ((row * 128 + 16 * g) ^ sw));
      short8 v1 = *reinterpret_cast<const short8*>(ldsV + ((row * 128 + 64 + 16 * g) ^ sw));
      ot[mt] = __builtin_amdgcn_mfma_f32_16x16x32_bf16(v0, pb[0], ot[mt], 0, 0, 0);
      ot[mt] = __builtin_amdgcn_mfma_f32_16x16x32_bf16(v1, pb[1], ot[mt], 0, 0, 0);
    }
    __syncthreads();
  }

  // epilogue: lane holds O^T[d = 16mt + 4g + r][q]; divide by l, store
  const float inv = 1.f / lrun;
  float* orow = ctx + (size_t)(b * N + qglob) * C + h * Dh;
#pragma unroll
  for (int mt = 0; mt < 4; ++mt) {
    float4 o;
    o.x = ot[mt][0] * inv; o.y = ot[mt][1] * inv;
    o.z = ot[mt][2] * inv; o.w = ot[mt][3] * inv;
    *reinterpret_cast<float4*>(orow + 16 * mt + 4 * g) = o;
  }
}

}  // namespace

extern "C" void kernel_launch(void* const* d_in, const int* in_sizes, int n_in,
                              void* d_out, int out_size, void* d_ws, size_t ws_size,
                              hipStream_t stream) {
  const float* x      = (const float*)d_in[0];
  const float* qkv_w  = (const float*)d_in[1];
  const float* qkv_b  = (const float*)d_in[2];
  const float* proj_w = (const float*)d_in[3];
  const float* proj_b = (const float*)d_in[4];
  float* out = (float*)d_out;

  unsigned short* qkvbf = (unsigned short*)d_ws;                       // 37.7 MB
  float* ctx = (float*)((char*)d_ws + (size_t)M * C3 * 2);             // 25.2 MB
  unsigned short* vt =
      (unsigned short*)((char*)ctx + (size_t)M * C * 4);               // 12.6 MB

  gemm_qkv_bf16<<<dim3(M / 64, C3 / 64), 256, 0, stream>>>(x, qkv_w, qkv_b, qkvbf);
  vt_prepass<<<dim3(B * H, N / 64), 256, 0, stream>>>(qkvbf, vt);
  attn_mfma<<<dim3(B * H, N / 64), 256, 0, stream>>>(qkvbf, vt, ctx);
  gemm_bt_bias<64, 64, 16>
      <<<dim3(M / 64, C / 64), 256, 0, stream>>>(ctx, proj_w, proj_b, out, M, C, C);
}

// Round 3
// 189.787 us; speedup vs baseline: 15.8465x; 4.6110x over previous
//
#include <hip/hip_runtime.h>
#include <math.h>

typedef __attribute__((ext_vector_type(8))) short short8;
typedef __attribute__((ext_vector_type(4))) float f32x4;

namespace {

constexpr int B  = 4;
constexpr int N  = 2048;
constexpr int C  = 768;
constexpr int H  = 12;
constexpr int Dh = 64;
constexpr int M  = B * N;      // 8192
constexpr int C3 = 3 * C;      // 2304

__device__ inline unsigned short f2bf(float x) {        // RTNE f32 -> bf16
  unsigned int u = __float_as_uint(x);
  return (unsigned short)((u + 0x7fffu + ((u >> 16) & 1u)) >> 16);
}

__device__ inline void gload_lds16(const void* g, void* lds) {
  __builtin_amdgcn_global_load_lds(
      (const __attribute__((address_space(1))) void*)g,
      (__attribute__((address_space(3))) void*)lds, 16, 0, 0);
}

// ---------------- f32 -> bf16 conversion (vectorized) ----------------
__global__ __launch_bounds__(256) void cvt_f32_bf16(
    const float* __restrict__ in, unsigned short* __restrict__ out, int n4) {
  int i = blockIdx.x * 256 + threadIdx.x;
  if (i < n4) {
    float4 v = reinterpret_cast<const float4*>(in)[i];
    ushort4 o;
    o.x = f2bf(v.x); o.y = f2bf(v.y); o.z = f2bf(v.z); o.w = f2bf(v.w);
    reinterpret_cast<ushort4*>(out)[i] = o;
  }
}

// ---------------- bf16 MFMA GEMM: out = A @ Bw^T + bias ----------------
// A: [Md][K] bf16 row-major, Bw: [Nd][K] bf16 row-major (torch Linear weight).
// m97 structure: 128x128 tile, BK=64, 4 waves (2x2 of 64x64), global_load_lds
// width 16, LDS linear + XOR swizzle via pre-swizzled global source (rule #21).
// QKV_EPI: bf16 out, bias then 0.125 scale on cols < C. else: f32 out + bias.
template <bool QKV_EPI>
__global__ __launch_bounds__(256, 2) void gemm_mfma_bt(
    const unsigned short* __restrict__ A, const unsigned short* __restrict__ Bw,
    const float* __restrict__ bias, void* __restrict__ outp, int Nd, int K) {
  __shared__ alignas(16) unsigned short lA[128 * 64];
  __shared__ alignas(16) unsigned short lB[128 * 64];
  const int t = threadIdx.x, wave = t >> 6, lane = t & 63;
  const int bm = blockIdx.x * 128, bn = blockIdx.y * 128;
  const int wr = (wave >> 1) * 64, wc = (wave & 1) * 64;

  f32x4 acc[4][4];
#pragma unroll
  for (int i = 0; i < 4; ++i)
#pragma unroll
    for (int j = 0; j < 4; ++j) acc[i][j] = (f32x4){0.f, 0.f, 0.f, 0.f};

  // staging: lane covers row srow of each 8-row group; source col pre-swizzled
  // so that linear LDS dest + XOR'd read address yields A[row][col].
  const int srow = lane >> 3;
  const int scol = ((lane & 7) ^ srow) * 8;   // element offset in [0,64)
  const int rb0  = wave * 32;                 // wave stages rows rb0..rb0+31

  for (int k0 = 0; k0 < K; k0 += 64) {
#pragma unroll
    for (int i = 0; i < 4; ++i) {
      const int rb = rb0 + i * 8;             // wave-uniform
      const unsigned short* ga = A  + (size_t)(bm + rb + srow) * K + k0 + scol;
      const unsigned short* gb = Bw + (size_t)(bn + rb + srow) * K + k0 + scol;
      gload_lds16(ga, (char*)lA + rb * 128);
      gload_lds16(gb, (char*)lB + rb * 128);
    }
    __syncthreads();

#pragma unroll
    for (int kc = 0; kc < 2; ++kc) {
      short8 af[4], bfr[4];
#pragma unroll
      for (int mt = 0; mt < 4; ++mt) {
        const int row = wr + mt * 16 + (lane & 15);
        const int q = (row * 128 + kc * 64 + (lane >> 4) * 16) ^ ((row & 7) << 4);
        af[mt] = *reinterpret_cast<const short8*>((const char*)lA + q);
      }
#pragma unroll
      for (int nt = 0; nt < 4; ++nt) {
        const int row = wc + nt * 16 + (lane & 15);
        const int q = (row * 128 + kc * 64 + (lane >> 4) * 16) ^ ((row & 7) << 4);
        bfr[nt] = *reinterpret_cast<const short8*>((const char*)lB + q);
      }
#pragma unroll
      for (int mt = 0; mt < 4; ++mt)
#pragma unroll
        for (int nt = 0; nt < 4; ++nt)
          acc[mt][nt] = __builtin_amdgcn_mfma_f32_16x16x32_bf16(
              af[mt], bfr[nt], acc[mt][nt], 0, 0, 0);
    }
    __syncthreads();
  }

  // epilogue: lane l reg r holds D[16mt + (l>>4)*4 + r][16nt + (l&15)]
  const int r0 = (lane >> 4) * 4;
  const int cl = lane & 15;
#pragma unroll
  for (int nt = 0; nt < 4; ++nt) {
    const int col = bn + wc + nt * 16 + cl;
    const float bs = bias[col];
    const float sc = (QKV_EPI && col < C) ? 0.125f : 1.0f;
#pragma unroll
    for (int mt = 0; mt < 4; ++mt) {
#pragma unroll
      for (int r = 0; r < 4; ++r) {
        const size_t row = bm + wr + mt * 16 + r0 + r;
        const float v = acc[mt][nt][r] + bs;
        if (QKV_EPI)
          ((unsigned short*)outp)[row * Nd + col] = f2bf(v * sc);
        else
          ((float*)outp)[row * Nd + col] = v;
      }
    }
  }
}

// ------------- V^T prepass: qkvbf V columns -> vt[b][h][d][n] (bf16) -------------
__global__ __launch_bounds__(256) void vt_prepass(
    const unsigned short* __restrict__ qkvbf, unsigned short* __restrict__ vt) {
  const int bh = blockIdx.x, b = bh / H, h = bh % H;
  const int nt = blockIdx.y;
  __shared__ unsigned short tile[64][72];
  const int t = threadIdx.x;
  const int r = t >> 2, ch = (t & 3) * 16;

  const unsigned short* src =
      qkvbf + (size_t)(b * N + nt * 64 + r) * C3 + 2 * C + h * Dh + ch;
  *reinterpret_cast<int4*>(&tile[r][ch])     = *reinterpret_cast<const int4*>(src);
  *reinterpret_cast<int4*>(&tile[r][ch + 8]) = *reinterpret_cast<const int4*>(src + 8);
  __syncthreads();

  alignas(16) unsigned short vals[16];
#pragma unroll
  for (int i = 0; i < 16; ++i) vals[i] = tile[ch + i][r];   // d = r, n = ch+i
  unsigned short* dst = vt + ((size_t)bh * Dh + r) * N + nt * 64 + ch;
  *reinterpret_cast<int4*>(dst)     = *reinterpret_cast<int4*>(&vals[0]);
  *reinterpret_cast<int4*>(dst + 8) = *reinterpret_cast<int4*>(&vals[8]);
}

// ------------- MFMA flash attention (writes bf16 ctx) -------------
__global__ __launch_bounds__(256) void attn_mfma(
    const unsigned short* __restrict__ qkvbf,
    const unsigned short* __restrict__ vt,
    unsigned short* __restrict__ ctx) {
  const int bh = blockIdx.x, b = bh / H, h = bh % H;
  const int qt = blockIdx.y;
  const int t = threadIdx.x;
  const int wave = t >> 6, lane = t & 63;
  const int q16 = lane & 15, g = lane >> 4;

  __shared__ alignas(16) char ldsK[64 * 128];   // [64 kv][64 d] bf16, swizzled
  __shared__ alignas(16) char ldsV[64 * 128];   // [64 d][64 kv] bf16, swizzled

  const int qglob = qt * 64 + wave * 16 + q16;

  short8 qf[2];
  {
    const unsigned short* qp = qkvbf + (size_t)(b * N + qglob) * C3 + h * Dh + g * 8;
    int4 v0 = *reinterpret_cast<const int4*>(qp);
    int4 v1 = *reinterpret_cast<const int4*>(qp + 32);
    qf[0] = *reinterpret_cast<short8*>(&v0);
    qf[1] = *reinterpret_cast<short8*>(&v1);
  }

  f32x4 ot[4];
#pragma unroll
  for (int mt = 0; mt < 4; ++mt) ot[mt] = (f32x4){0.f, 0.f, 0.f, 0.f};
  float mrun = -INFINITY, lrun = 0.f;

  const int sr = t >> 2;
  const int scB = (t & 3) * 32;
  const size_t kgbase = (size_t)(b * N) * C3 + C + h * Dh;
  const unsigned short* vtrow = vt + ((size_t)bh * Dh + sr) * N;

  for (int kt = 0; kt < N / 64; ++kt) {
    {
      const unsigned short* kp = qkvbf + kgbase + (size_t)(kt * 64 + sr) * C3 + (t & 3) * 16;
      int4 ka = *reinterpret_cast<const int4*>(kp);
      int4 kb = *reinterpret_cast<const int4*>(kp + 8);
      const unsigned short* vp = vtrow + kt * 64 + (t & 3) * 16;
      int4 va = *reinterpret_cast<const int4*>(vp);
      int4 vb = *reinterpret_cast<const int4*>(vp + 8);
      const int base = sr * 128 + scB, sw = (sr & 7) << 4;
      *reinterpret_cast<int4*>(ldsK + ((base) ^ sw))      = ka;
      *reinterpret_cast<int4*>(ldsK + ((base + 16) ^ sw)) = kb;
      *reinterpret_cast<int4*>(ldsV + ((base) ^ sw))      = va;
      *reinterpret_cast<int4*>(ldsV + ((base + 16) ^ sw)) = vb;
    }
    __syncthreads();

    f32x4 st[4];
#pragma unroll
    for (int mt = 0; mt < 4; ++mt) {
      const int row = 16 * mt + q16, sw = (row & 7) << 4;
      short8 k0 = *reinterpret_cast<const short8*>(ldsK + ((row * 128 + 16 * g) ^ sw));
      short8 k1 = *reinterpret_cast<const short8*>(ldsK + ((row * 128 + 64 + 16 * g) ^ sw));
      f32x4 z = (f32x4){0.f, 0.f, 0.f, 0.f};
      f32x4 p = __builtin_amdgcn_mfma_f32_16x16x32_bf16(k0, qf[0], z, 0, 0, 0);
      st[mt]  = __builtin_amdgcn_mfma_f32_16x16x32_bf16(k1, qf[1], p, 0, 0, 0);
    }

    float mx = st[0][0];
#pragma unroll
    for (int tt = 0; tt < 4; ++tt)
#pragma unroll
      for (int r = 0; r < 4; ++r) mx = fmaxf(mx, st[tt][r]);
    mx = fmaxf(mx, __shfl_xor(mx, 16));
    mx = fmaxf(mx, __shfl_xor(mx, 32));
    const float nm = fmaxf(mrun, mx);
    const float corr = __expf(mrun - nm);
    mrun = nm;

    float ls = 0.f;
    unsigned int w0[4], w1[4];
#pragma unroll
    for (int tt = 0; tt < 4; ++tt) {
      float p0 = __expf(st[tt][0] - nm), p1 = __expf(st[tt][1] - nm);
      float p2 = __expf(st[tt][2] - nm), p3 = __expf(st[tt][3] - nm);
      ls += (p0 + p1) + (p2 + p3);
      w0[tt] = (unsigned)f2bf(p0) | ((unsigned)f2bf(p1) << 16);
      w1[tt] = (unsigned)f2bf(p2) | ((unsigned)f2bf(p3) << 16);
    }
    ls += __shfl_xor(ls, 16);
    ls += __shfl_xor(ls, 32);
    lrun = lrun * corr + ls;
#pragma unroll
    for (int mt = 0; mt < 4; ++mt) ot[mt] = ot[mt] * corr;

    short8 pb[2];
    const int srcA = q16 + ((lane & 16) ? 32 : 0);
    const int srcB = srcA + 16;
    const bool hi = (lane & 32) != 0;
#pragma unroll
    for (int c = 0; c < 2; ++c) {
      unsigned a0l = (unsigned)__shfl((int)w0[2 * c], srcA);
      unsigned a1l = (unsigned)__shfl((int)w1[2 * c], srcA);
      unsigned b0l = (unsigned)__shfl((int)w0[2 * c], srcB);
      unsigned b1l = (unsigned)__shfl((int)w1[2 * c], srcB);
      unsigned a0h = (unsigned)__shfl((int)w0[2 * c + 1], srcA);
      unsigned a1h = (unsigned)__shfl((int)w1[2 * c + 1], srcA);
      unsigned b0h = (unsigned)__shfl((int)w0[2 * c + 1], srcB);
      unsigned b1h = (unsigned)__shfl((int)w1[2 * c + 1], srcB);
      int4 pw;
      pw.x = (int)(hi ? a0h : a0l);
      pw.y = (int)(hi ? a1h : a1l);
      pw.z = (int)(hi ? b0h : b0l);
      pw.w = (int)(hi ? b1h : b1l);
      pb[c] = *reinterpret_cast<short8*>(&pw);
    }

#pragma unroll
    for (int mt = 0; mt < 4; ++mt) {
      const int row = 16 * mt + q16, sw = (row & 7) << 4;
      short8 v0 = *reinterpret_cast<const short8*>(ldsV + ((row * 128 + 16 * g) ^ sw));
      short8 v1 = *reinterpret_cast<const short8*>(ldsV + ((row * 128 + 64 + 16 * g) ^ sw));
      ot[mt] = __builtin_amdgcn_mfma_f32_16x16x32_bf16(v0, pb[0], ot[mt], 0, 0, 0);
      ot[mt] = __builtin_amdgcn_mfma_f32_16x16x32_bf16(v1, pb[1], ot[mt], 0, 0, 0);
    }
    __syncthreads();
  }

  const float inv = 1.f / lrun;
  unsigned short* orow = ctx + (size_t)(b * N + qglob) * C + h * Dh;
#pragma unroll
  for (int mt = 0; mt < 4; ++mt) {
    ushort4 o;
    o.x = f2bf(ot[mt][0] * inv);
    o.y = f2bf(ot[mt][1] * inv);
    o.z = f2bf(ot[mt][2] * inv);
    o.w = f2bf(ot[mt][3] * inv);
    *reinterpret_cast<ushort4*>(orow + 16 * mt + 4 * g) = o;
  }
}

}  // namespace

extern "C" void kernel_launch(void* const* d_in, const int* in_sizes, int n_in,
                              void* d_out, int out_size, void* d_ws, size_t ws_size,
                              hipStream_t stream) {
  const float* x      = (const float*)d_in[0];
  const float* qkv_w  = (const float*)d_in[1];
  const float* qkv_b  = (const float*)d_in[2];
  const float* proj_w = (const float*)d_in[3];
  const float* proj_b = (const float*)d_in[4];
  float* out = (float*)d_out;

  unsigned short* qkvbf = (unsigned short*)d_ws;               // [M][C3]
  unsigned short* ctx   = qkvbf + (size_t)M * C3;              // [M][C] bf16
  unsigned short* vt    = ctx + (size_t)M * C;                 // [B*H][Dh][N]
  unsigned short* xbf   = vt + (size_t)M * C;                  // [M][C]
  unsigned short* wqkv  = xbf + (size_t)M * C;                 // [C3][C]
  unsigned short* wproj = wqkv + (size_t)C3 * C;               // [C][C]

  cvt_f32_bf16<<<(M * C / 4 + 255) / 256, 256, 0, stream>>>(x, xbf, M * C / 4);
  cvt_f32_bf16<<<(C3 * C / 4 + 255) / 256, 256, 0, stream>>>(qkv_w, wqkv, C3 * C / 4);
  cvt_f32_bf16<<<(C * C / 4 + 255) / 256, 256, 0, stream>>>(proj_w, wproj, C * C / 4);

  gemm_mfma_bt<true>
      <<<dim3(M / 128, C3 / 128), 256, 0, stream>>>(xbf, wqkv, qkv_b, qkvbf, C3, C);
  vt_prepass<<<dim3(B * H, N / 64), 256, 0, stream>>>(qkvbf, vt);
  attn_mfma<<<dim3(B * H, N / 64), 256, 0, stream>>>(qkvbf, vt, ctx);
  gemm_mfma_bt<false>
      <<<dim3(M / 128, C / 128), 256, 0, stream>>>(ctx, wproj, proj_b, out, C, C);
}

// Round 4
// 182.249 us; speedup vs baseline: 16.5019x; 1.0414x over previous
//
#include <hip/hip_runtime.h>
#include <math.h>

typedef __attribute__((ext_vector_type(8))) short short8;
typedef __attribute__((ext_vector_type(4))) float f32x4;

namespace {

constexpr int B  = 4;
constexpr int N  = 2048;
constexpr int C  = 768;
constexpr int H  = 12;
constexpr int Dh = 64;
constexpr int M  = B * N;      // 8192
constexpr int C3 = 3 * C;      // 2304

// attention scale folded with log2(e): S = (q*QSCALE)·k is in log2 domain,
// so softmax uses bare v_exp_f32 (exp2) with no per-element multiply.
constexpr float QSCALE = 0.125f * 1.4426950408889634f;

__device__ inline unsigned short f2bf(float x) {        // RTNE f32 -> bf16
  unsigned int u = __float_as_uint(x);
  return (unsigned short)((u + 0x7fffu + ((u >> 16) & 1u)) >> 16);
}

__device__ inline unsigned cvt_pk_bf16(float lo, float hi) {  // T12
  unsigned r;
  asm("v_cvt_pk_bf16_f32 %0, %1, %2" : "=v"(r) : "v"(lo), "v"(hi));
  return r;
}

__device__ inline void gload_lds16(const void* g, void* lds) {
  __builtin_amdgcn_global_load_lds(
      (const __attribute__((address_space(1))) void*)g,
      (__attribute__((address_space(3))) void*)lds, 16, 0, 0);
}

// ---------------- f32 -> bf16 conversion (vectorized) ----------------
__global__ __launch_bounds__(256) void cvt_f32_bf16(
    const float* __restrict__ in, unsigned short* __restrict__ out, int n4) {
  int i = blockIdx.x * 256 + threadIdx.x;
  if (i < n4) {
    float4 v = reinterpret_cast<const float4*>(in)[i];
    ushort4 o;
    o.x = f2bf(v.x); o.y = f2bf(v.y); o.z = f2bf(v.z); o.w = f2bf(v.w);
    reinterpret_cast<ushort4*>(out)[i] = o;
  }
}

// ---------------- bf16 MFMA GEMM: out = A @ Bw^T + bias ----------------
template <bool QKV_EPI>
__global__ __launch_bounds__(256, 2) void gemm_mfma_bt(
    const unsigned short* __restrict__ A, const unsigned short* __restrict__ Bw,
    const float* __restrict__ bias, void* __restrict__ outp, int Nd, int K) {
  __shared__ alignas(16) unsigned short lA[128 * 64];
  __shared__ alignas(16) unsigned short lB[128 * 64];
  const int t = threadIdx.x, wave = t >> 6, lane = t & 63;
  const int bm = blockIdx.x * 128, bn = blockIdx.y * 128;
  const int wr = (wave >> 1) * 64, wc = (wave & 1) * 64;

  f32x4 acc[4][4];
#pragma unroll
  for (int i = 0; i < 4; ++i)
#pragma unroll
    for (int j = 0; j < 4; ++j) acc[i][j] = (f32x4){0.f, 0.f, 0.f, 0.f};

  const int srow = lane >> 3;
  const int scol = ((lane & 7) ^ srow) * 8;   // pre-swizzled source col
  const int rb0  = wave * 32;

  for (int k0 = 0; k0 < K; k0 += 64) {
#pragma unroll
    for (int i = 0; i < 4; ++i) {
      const int rb = rb0 + i * 8;
      const unsigned short* ga = A  + (size_t)(bm + rb + srow) * K + k0 + scol;
      const unsigned short* gb = Bw + (size_t)(bn + rb + srow) * K + k0 + scol;
      gload_lds16(ga, (char*)lA + rb * 128);
      gload_lds16(gb, (char*)lB + rb * 128);
    }
    __syncthreads();

#pragma unroll
    for (int kc = 0; kc < 2; ++kc) {
      short8 af[4], bfr[4];
#pragma unroll
      for (int mt = 0; mt < 4; ++mt) {
        const int row = wr + mt * 16 + (lane & 15);
        const int q = (row * 128 + kc * 64 + (lane >> 4) * 16) ^ ((row & 7) << 4);
        af[mt] = *reinterpret_cast<const short8*>((const char*)lA + q);
      }
#pragma unroll
      for (int nt = 0; nt < 4; ++nt) {
        const int row = wc + nt * 16 + (lane & 15);
        const int q = (row * 128 + kc * 64 + (lane >> 4) * 16) ^ ((row & 7) << 4);
        bfr[nt] = *reinterpret_cast<const short8*>((const char*)lB + q);
      }
#pragma unroll
      for (int mt = 0; mt < 4; ++mt)
#pragma unroll
        for (int nt = 0; nt < 4; ++nt)
          acc[mt][nt] = __builtin_amdgcn_mfma_f32_16x16x32_bf16(
              af[mt], bfr[nt], acc[mt][nt], 0, 0, 0);
    }
    __syncthreads();
  }

  const int r0 = (lane >> 4) * 4;
  const int cl = lane & 15;
#pragma unroll
  for (int nt = 0; nt < 4; ++nt) {
    const int col = bn + wc + nt * 16 + cl;
    const float bs = bias[col];
    const float sc = (QKV_EPI && col < C) ? QSCALE : 1.0f;
#pragma unroll
    for (int mt = 0; mt < 4; ++mt) {
#pragma unroll
      for (int r = 0; r < 4; ++r) {
        const size_t row = bm + wr + mt * 16 + r0 + r;
        const float v = acc[mt][nt][r] + bs;
        if (QKV_EPI)
          ((unsigned short*)outp)[row * Nd + col] = f2bf(v * sc);
        else
          ((float*)outp)[row * Nd + col] = v;
      }
    }
  }
}

// ------------- V^T prepass: qkvbf V columns -> vt[b][h][d][n] (bf16) -------------
__global__ __launch_bounds__(256) void vt_prepass(
    const unsigned short* __restrict__ qkvbf, unsigned short* __restrict__ vt) {
  const int bh = blockIdx.x, b = bh / H, h = bh % H;
  const int nt = blockIdx.y;
  __shared__ unsigned short tile[64][72];
  const int t = threadIdx.x;
  const int r = t >> 2, ch = (t & 3) * 16;

  const unsigned short* src =
      qkvbf + (size_t)(b * N + nt * 64 + r) * C3 + 2 * C + h * Dh + ch;
  *reinterpret_cast<int4*>(&tile[r][ch])     = *reinterpret_cast<const int4*>(src);
  *reinterpret_cast<int4*>(&tile[r][ch + 8]) = *reinterpret_cast<const int4*>(src + 8);
  __syncthreads();

  alignas(16) unsigned short vals[16];
#pragma unroll
  for (int i = 0; i < 16; ++i) vals[i] = tile[ch + i][r];   // d = r, n = ch+i
  unsigned short* dst = vt + ((size_t)bh * Dh + r) * N + nt * 64 + ch;
  *reinterpret_cast<int4*>(dst)     = *reinterpret_cast<int4*>(&vals[0]);
  *reinterpret_cast<int4*>(dst + 8) = *reinterpret_cast<int4*>(&vals[8]);
}

// ------------- MFMA flash attention (exp2-domain, defer-max, async stage) -------------
__global__ __launch_bounds__(256) void attn_mfma(
    const unsigned short* __restrict__ qkvbf,
    const unsigned short* __restrict__ vt,
    unsigned short* __restrict__ ctx) {
  const int bh = blockIdx.x, b = bh / H, h = bh % H;
  const int qt = blockIdx.y;
  const int t = threadIdx.x;
  const int wave = t >> 6, lane = t & 63;
  const int q16 = lane & 15, g = lane >> 4;

  __shared__ alignas(16) char ldsK[64 * 128];   // [64 kv][64 d] bf16, swizzled
  __shared__ alignas(16) char ldsV[64 * 128];   // [64 d][64 kv] bf16, swizzled

  const int qglob = qt * 64 + wave * 16 + q16;

  short8 qf[2];
  {
    const unsigned short* qp = qkvbf + (size_t)(b * N + qglob) * C3 + h * Dh + g * 8;
    int4 v0 = *reinterpret_cast<const int4*>(qp);
    int4 v1 = *reinterpret_cast<const int4*>(qp + 32);
    qf[0] = *reinterpret_cast<short8*>(&v0);
    qf[1] = *reinterpret_cast<short8*>(&v1);
  }

  f32x4 ot[4];
#pragma unroll
  for (int mt = 0; mt < 4; ++mt) ot[mt] = (f32x4){0.f, 0.f, 0.f, 0.f};
  float mrun = -INFINITY, lrun = 0.f;

  const int sr = t >> 2;
  const int scB = (t & 3) * 32;
  const size_t kgbase = (size_t)(b * N) * C3 + C + h * Dh;
  const unsigned short* vtrow = vt + ((size_t)bh * Dh + sr) * N;

  // T14: async-STAGE split — regs hold the next tile while compute runs.
  int4 ka, kb, va, vb;
  auto load_tile = [&](int kt) {
    const unsigned short* kp =
        qkvbf + kgbase + (size_t)(kt * 64 + sr) * C3 + (t & 3) * 16;
    ka = *reinterpret_cast<const int4*>(kp);
    kb = *reinterpret_cast<const int4*>(kp + 8);
    const unsigned short* vp = vtrow + kt * 64 + (t & 3) * 16;
    va = *reinterpret_cast<const int4*>(vp);
    vb = *reinterpret_cast<const int4*>(vp + 8);
  };
  load_tile(0);

  const int base = sr * 128 + scB, sw0 = (sr & 7) << 4;
  constexpr int NT = N / 64;

  for (int kt = 0; kt < NT; ++kt) {
    *reinterpret_cast<int4*>(ldsK + ((base) ^ sw0))      = ka;
    *reinterpret_cast<int4*>(ldsK + ((base + 16) ^ sw0)) = kb;
    *reinterpret_cast<int4*>(ldsV + ((base) ^ sw0))      = va;
    *reinterpret_cast<int4*>(ldsV + ((base + 16) ^ sw0)) = vb;
    __syncthreads();
    if (kt + 1 < NT) load_tile(kt + 1);   // overlaps with compute below

    f32x4 st[4];
#pragma unroll
    for (int mt = 0; mt < 4; ++mt) {
      const int row = 16 * mt + q16, sw = (row & 7) << 4;
      short8 k0 = *reinterpret_cast<const short8*>(ldsK + ((row * 128 + 16 * g) ^ sw));
      short8 k1 = *reinterpret_cast<const short8*>(ldsK + ((row * 128 + 64 + 16 * g) ^ sw));
      f32x4 z = (f32x4){0.f, 0.f, 0.f, 0.f};
      f32x4 p = __builtin_amdgcn_mfma_f32_16x16x32_bf16(k0, qf[0], z, 0, 0, 0);
      st[mt]  = __builtin_amdgcn_mfma_f32_16x16x32_bf16(k1, qf[1], p, 0, 0, 0);
    }

    // tile max (pairwise tree), reduce across the 4 kv-groups
    float m0 = fmaxf(fmaxf(st[0][0], st[0][1]), fmaxf(st[0][2], st[0][3]));
    float m1 = fmaxf(fmaxf(st[1][0], st[1][1]), fmaxf(st[1][2], st[1][3]));
    float m2 = fmaxf(fmaxf(st[2][0], st[2][1]), fmaxf(st[2][2], st[2][3]));
    float m3 = fmaxf(fmaxf(st[3][0], st[3][1]), fmaxf(st[3][2], st[3][3]));
    float mx = fmaxf(fmaxf(m0, m1), fmaxf(m2, m3));
    mx = fmaxf(mx, __shfl_xor(mx, 16));
    mx = fmaxf(mx, __shfl_xor(mx, 32));

    // T13 defer-max: rescale only when the max grew by >8 (log2 units)
    const float nm = fmaxf(mrun, mx);
    if (nm - mrun > 8.f) {
      const float corr = __builtin_amdgcn_exp2f(mrun - nm);  // first tile: 0
      lrun *= corr;
#pragma unroll
      for (int mt = 0; mt < 4; ++mt) ot[mt] = ot[mt] * corr;
      mrun = nm;
    }

    float ls = 0.f;
    unsigned int w0[4], w1[4];
#pragma unroll
    for (int tt = 0; tt < 4; ++tt) {
      float p0 = __builtin_amdgcn_exp2f(st[tt][0] - mrun);
      float p1 = __builtin_amdgcn_exp2f(st[tt][1] - mrun);
      float p2 = __builtin_amdgcn_exp2f(st[tt][2] - mrun);
      float p3 = __builtin_amdgcn_exp2f(st[tt][3] - mrun);
      ls += (p0 + p1) + (p2 + p3);
      w0[tt] = cvt_pk_bf16(p0, p1);
      w1[tt] = cvt_pk_bf16(p2, p3);
    }
    ls += __shfl_xor(ls, 16);
    ls += __shfl_xor(ls, 32);
    lrun += ls;

    // build PV B-frags: lane needs P[q=lane&15][kv = 32c + 8g + j]
    short8 pb[2];
    const int srcA = q16 + ((lane & 16) ? 32 : 0);
    const int srcB = srcA + 16;
    const bool hi = (lane & 32) != 0;
#pragma unroll
    for (int c = 0; c < 2; ++c) {
      unsigned a0l = (unsigned)__shfl((int)w0[2 * c], srcA);
      unsigned a1l = (unsigned)__shfl((int)w1[2 * c], srcA);
      unsigned b0l = (unsigned)__shfl((int)w0[2 * c], srcB);
      unsigned b1l = (unsigned)__shfl((int)w1[2 * c], srcB);
      unsigned a0h = (unsigned)__shfl((int)w0[2 * c + 1], srcA);
      unsigned a1h = (unsigned)__shfl((int)w1[2 * c + 1], srcA);
      unsigned b0h = (unsigned)__shfl((int)w0[2 * c + 1], srcB);
      unsigned b1h = (unsigned)__shfl((int)w1[2 * c + 1], srcB);
      int4 pw;
      pw.x = (int)(hi ? a0h : a0l);
      pw.y = (int)(hi ? a1h : a1l);
      pw.z = (int)(hi ? b0h : b0l);
      pw.w = (int)(hi ? b1h : b1l);
      pb[c] = *reinterpret_cast<short8*>(&pw);
    }

#pragma unroll
    for (int mt = 0; mt < 4; ++mt) {
      const int row = 16 * mt + q16, sw = (row & 7) << 4;
      short8 v0 = *reinterpret_cast<const short8*>(ldsV + ((row * 128 + 16 * g) ^ sw));
      short8 v1 = *reinterpret_cast<const short8*>(ldsV + ((row * 128 + 64 + 16 * g) ^ sw));
      ot[mt] = __builtin_amdgcn_mfma_f32_16x16x32_bf16(v0, pb[0], ot[mt], 0, 0, 0);
      ot[mt] = __builtin_amdgcn_mfma_f32_16x16x32_bf16(v1, pb[1], ot[mt], 0, 0, 0);
    }
    __syncthreads();
  }

  const float inv = 1.f / lrun;
  unsigned short* orow = ctx + (size_t)(b * N + qglob) * C + h * Dh;
#pragma unroll
  for (int mt = 0; mt < 4; ++mt) {
    ushort4 o;
    o.x = f2bf(ot[mt][0] * inv);
    o.y = f2bf(ot[mt][1] * inv);
    o.z = f2bf(ot[mt][2] * inv);
    o.w = f2bf(ot[mt][3] * inv);
    *reinterpret_cast<ushort4*>(orow + 16 * mt + 4 * g) = o;
  }
}

}  // namespace

extern "C" void kernel_launch(void* const* d_in, const int* in_sizes, int n_in,
                              void* d_out, int out_size, void* d_ws, size_t ws_size,
                              hipStream_t stream) {
  const float* x      = (const float*)d_in[0];
  const float* qkv_w  = (const float*)d_in[1];
  const float* qkv_b  = (const float*)d_in[2];
  const float* proj_w = (const float*)d_in[3];
  const float* proj_b = (const float*)d_in[4];
  float* out = (float*)d_out;

  unsigned short* qkvbf = (unsigned short*)d_ws;               // [M][C3]
  unsigned short* ctx   = qkvbf + (size_t)M * C3;              // [M][C] bf16
  unsigned short* vt    = ctx + (size_t)M * C;                 // [B*H][Dh][N]
  unsigned short* xbf   = vt + (size_t)M * C;                  // [M][C]
  unsigned short* wqkv  = xbf + (size_t)M * C;                 // [C3][C]
  unsigned short* wproj = wqkv + (size_t)C3 * C;               // [C][C]

  cvt_f32_bf16<<<(M * C / 4 + 255) / 256, 256, 0, stream>>>(x, xbf, M * C / 4);
  cvt_f32_bf16<<<(C3 * C / 4 + 255) / 256, 256, 0, stream>>>(qkv_w, wqkv, C3 * C / 4);
  cvt_f32_bf16<<<(C * C / 4 + 255) / 256, 256, 0, stream>>>(proj_w, wproj, C * C / 4);

  gemm_mfma_bt<true>
      <<<dim3(M / 128, C3 / 128), 256, 0, stream>>>(xbf, wqkv, qkv_b, qkvbf, C3, C);
  vt_prepass<<<dim3(B * H, N / 64), 256, 0, stream>>>(qkvbf, vt);
  attn_mfma<<<dim3(B * H, N / 64), 256, 0, stream>>>(qkvbf, vt, ctx);
  gemm_mfma_bt<false>
      <<<dim3(M / 128, C / 128), 256, 0, stream>>>(ctx, wproj, proj_b, out, C, C);
}